// Round 6
// baseline (140.880 us; speedup 1.0000x reference)
//
#include <hip/hip_runtime.h>

#define U_N 100000
#define I_N 100000
#define D_N 64
#define B_N 16384
#define T_N 1638400
#define R_N 5
#define NSEG (B_N * R_N)         // 81920 segments

#define RS_THREADS (I_N * 16)            // rowsum: 16 threads/row      = 1,600,000
#define BD_THREADS (T_N / 4)             // boundaries: 4 elems/thread  =   409,600
#define DOT_THREADS (B_N * 64)           // emb dot: 1 wave/sample      = 1,048,576
#define K1_THREADS (RS_THREADS + BD_THREADS + DOT_THREADS)  // = 3,058,176 (=11946*256)

// ---------------------------------------------------------------------------
// Kernel 1 (3-way fused, independent parts):
//  (a) rowsum[i] = sum_d Mr[i][d]
//  (b) seg_start[s] = first t with seg_ids[t] >= s   (linear transition scan)
//  (c) pre[b] = dot(ue,ie)+biases+g ; isum[b] = sum(ie)   (emb part of sample)
// ---------------------------------------------------------------------------
__global__ void prep_kernel(const float* __restrict__ Mr,
                            const int* __restrict__ seg_ids,
                            const int* __restrict__ user_idx,
                            const int* __restrict__ item_idx,
                            const float* __restrict__ user_emb,
                            const float* __restrict__ item_emb,
                            const float* __restrict__ user_bias,
                            const float* __restrict__ item_bias,
                            const float* __restrict__ global_avg,
                            float* __restrict__ rowsum,
                            int* __restrict__ seg_start,
                            float2* __restrict__ pre_isum) {
    int gtid = blockIdx.x * blockDim.x + threadIdx.x;
    if (gtid < RS_THREADS) {
        int row = gtid >> 4;
        int sub = gtid & 15;
        const float4* p = (const float4*)(Mr + (long)row * D_N);
        float4 v4 = p[sub];
        float v = v4.x + v4.y + v4.z + v4.w;
        v += __shfl_xor(v, 1);
        v += __shfl_xor(v, 2);
        v += __shfl_xor(v, 4);
        v += __shfl_xor(v, 8);
        if (sub == 0) rowsum[row] = v;
    } else if (gtid < RS_THREADS + BD_THREADS) {
        int t4 = gtid - RS_THREADS;
        int base = t4 * 4;
        int4 s4 = ((const int4*)seg_ids)[t4];
        int sv0 = (base == 0) ? -1 : seg_ids[base - 1];
        int sv1 = s4.x, sv2 = s4.y, sv3 = s4.z, sv4 = s4.w;
        for (int s = sv0 + 1; s <= sv1; ++s) seg_start[s] = base + 0;
        for (int s = sv1 + 1; s <= sv2; ++s) seg_start[s] = base + 1;
        for (int s = sv2 + 1; s <= sv3; ++s) seg_start[s] = base + 2;
        for (int s = sv3 + 1; s <= sv4; ++s) seg_start[s] = base + 3;
        if (base + 4 == T_N) {
            for (int s = sv4 + 1; s <= NSEG; ++s) seg_start[s] = T_N;
        }
    } else {
        int gt2  = gtid - (RS_THREADS + BD_THREADS);
        int b    = gt2 >> 6;
        int lane = gt2 & 63;
        int u      = user_idx[b];
        int target = item_idx[b];
        float ue = user_emb[(long)u * D_N + lane];
        float ie = item_emb[(long)target * D_N + lane];
        float ub = user_bias[u];           // broadcast, L2
        float ib = item_bias[target];
        float g  = global_avg[0];
        float dot = ue * ie;
        float isum = ie;
        #pragma unroll
        for (int off = 32; off >= 1; off >>= 1) {
            dot  += __shfl_xor(dot, off);
            isum += __shfl_xor(isum, off);
        }
        if (lane == 0) {
            float2 r;
            r.x = dot + ub + ib + g;
            r.y = isum;
            pre_isum[b] = r;
        }
    }
}

// ---------------------------------------------------------------------------
// Kernel 2: scan-only, one wave per sample. One aligned int4 load per lane
// covers 256 elements (range avg = 100); ratings are positional from the 6
// segment boundaries; matches counted via cold ballot path; single register
// accumulator, 6-shuffle reduction, combine with precomputed pre/isum.
// ---------------------------------------------------------------------------
__global__ void sample_kernel(const int* __restrict__ item_idx,
                              const int* __restrict__ flat_items,
                              const float* __restrict__ rowsum,
                              const int* __restrict__ seg_start,
                              const float2* __restrict__ pre_isum,
                              float* __restrict__ out) {
    int lane = threadIdx.x & 63;
    int b    = (blockIdx.x * blockDim.x + threadIdx.x) >> 6;
    if (b >= B_N) return;

    int target = item_idx[b];
    float2 pi  = pre_isum[b];            // broadcast load, early

    int e0 = seg_start[b * R_N + 0];
    int e1 = seg_start[b * R_N + 1];
    int e2 = seg_start[b * R_N + 2];
    int e3 = seg_start[b * R_N + 3];
    int e4 = seg_start[b * R_N + 4];
    int e5 = seg_start[b * R_N + 5];
    int lo = e0, hi = e5;

    int base = lo & ~3;                  // 16B-aligned start
    int t0 = base + 4 * lane;

    int4 fi4 = make_int4(-1, -1, -1, -1);
    if (t0 < hi) fi4 = ((const int4*)(flat_items + base))[lane];
    int  fi[4] = {fi4.x, fi4.y, fi4.z, fi4.w};
    bool ok[4], mt[4];
    int  rj[4];
    float rv[4] = {0.f, 0.f, 0.f, 0.f};
    #pragma unroll
    for (int j = 0; j < 4; ++j) {
        int t = t0 + j;
        ok[j] = (t >= lo) & (t < hi);
        rj[j] = (t >= e1) + (t >= e2) + (t >= e3) + (t >= e4);
        mt[j] = ok[j] && (fi[j] == target);
    }
    #pragma unroll
    for (int j = 0; j < 4; ++j) {
        if (ok[j]) rv[j] = rowsum[fi[j]];
    }

    // ---- match counts (cold: matches ~0.001/sample) ----
    int mcnt[R_N] = {0, 0, 0, 0, 0};
    unsigned long long anym = __ballot(mt[0] | mt[1] | mt[2] | mt[3]);
    if (anym) {
        #pragma unroll
        for (int j = 0; j < 4; ++j) {
            #pragma unroll
            for (int r = 0; r < R_N; ++r) {
                mcnt[r] += __popcll(__ballot(mt[j] && rj[j] == r));
            }
        }
    }
    // rare tail: range longer than 256-3
    for (int tb = base + 256; tb < hi; tb += 64) {
        int t = tb + lane;
        bool okt = t < hi;
        int f = okt ? flat_items[t] : -1;
        unsigned long long m = __ballot(okt && f == target);
        if (m) {
            int r = (t >= e1) + (t >= e2) + (t >= e3) + (t >= e4);
            #pragma unroll
            for (int rr = 0; rr < R_N; ++rr) {
                mcnt[rr] += __popcll(m & __ballot(r == rr));
            }
        }
    }

    // ---- per-rating weights (wave-uniform) ----
    int c0 = (e1 - e0) - mcnt[0];
    int c1 = (e2 - e1) - mcnt[1];
    int c2 = (e3 - e2) - mcnt[2];
    int c3 = (e4 - e3) - mcnt[3];
    int c4 = (e5 - e4) - mcnt[4];
    float w0 = c0 > 0 ? rsqrtf((float)c0) : 0.f;
    float w1 = c1 > 0 ? rsqrtf((float)c1) : 0.f;
    float w2 = c2 > 0 ? rsqrtf((float)c2) : 0.f;
    float w3 = c3 > 0 ? rsqrtf((float)c3) : 0.f;
    float w4 = c4 > 0 ? rsqrtf((float)c4) : 0.f;

    // ---- weighted accumulate (all in registers) ----
    float acc = 0.f;
    #pragma unroll
    for (int j = 0; j < 4; ++j) {
        if (ok[j] && !mt[j]) {
            int r = rj[j];
            float w = r == 0 ? w0 : (r == 1 ? w1 : (r == 2 ? w2 : (r == 3 ? w3 : w4)));
            acc += rv[j] * w;
        }
    }
    for (int tb = base + 256; tb < hi; tb += 64) {
        int t = tb + lane;
        if (t < hi) {
            int f = flat_items[t];
            if (f != target) {
                int r = (t >= e1) + (t >= e2) + (t >= e3) + (t >= e4);
                float w = r == 0 ? w0 : (r == 1 ? w1 : (r == 2 ? w2 : (r == 3 ? w3 : w4)));
                acc += rowsum[f] * w;
            }
        }
    }

    #pragma unroll
    for (int off = 32; off >= 1; off >>= 1) acc += __shfl_xor(acc, off);

    if (lane == 0) {
        float rui = pi.x + acc * pi.y;
        rui = fminf(fmaxf(rui, 1.0f), 5.0f);
        out[b] = rui;
    }
}

extern "C" void kernel_launch(void* const* d_in, const int* in_sizes, int n_in,
                              void* d_out, int out_size, void* d_ws, size_t ws_size,
                              hipStream_t stream) {
    const int*   user_idx   = (const int*)d_in[0];
    const int*   item_idx   = (const int*)d_in[1];
    const int*   flat_items = (const int*)d_in[2];
    const int*   seg_ids    = (const int*)d_in[3];
    const float* user_emb   = (const float*)d_in[4];
    const float* item_emb   = (const float*)d_in[5];
    const float* Mr         = (const float*)d_in[6];
    const float* user_bias  = (const float*)d_in[7];
    const float* item_bias  = (const float*)d_in[8];
    const float* global_avg = (const float*)d_in[9];
    float* out = (float*)d_out;

    // ws layout (16B-aligned sections):
    //   rowsum    : I_N floats            @ 0
    //   seg_start : NSEG+1 ints (pad 3)   @ 400,000 B
    //   pre_isum  : B_N float2            @ 400,000 + 327,696 = 727,696 B
    float*  rowsum    = (float*)d_ws;
    int*    seg_start = (int*)((char*)d_ws + 400000);
    float2* pre_isum  = (float2*)((char*)d_ws + 400000 + 327696);

    prep_kernel<<<K1_THREADS / 256, 256, 0, stream>>>(
        Mr, seg_ids, user_idx, item_idx, user_emb, item_emb,
        user_bias, item_bias, global_avg, rowsum, seg_start, pre_isum);
    sample_kernel<<<B_N / 4, 256, 0, stream>>>(
        item_idx, flat_items, rowsum, seg_start, pre_isum, out);
}

// Round 7
// 138.621 us; speedup vs baseline: 1.0163x; 1.0163x over previous
//
#include <hip/hip_runtime.h>

#define U_N 100000
#define I_N 100000
#define D_N 64
#define B_N 16384
#define T_N 1638400
#define R_N 5
#define NSEG (B_N * R_N)         // 81920 segments

#define RS_THREADS (I_N * 16)    // rowsum: 16 threads/row
#define BD_THREADS (T_N / 4)     // boundaries: 4 elems/thread
#define K1_THREADS (RS_THREADS + BD_THREADS)

// ---------------------------------------------------------------------------
// Kernel 1 (fused, independent parts):
//  (a) rowsum[i] = sum_d Mr[i][d]
//  (b) seg_start[s] = first t with seg_ids[t] >= s  (linear transition scan)
// ---------------------------------------------------------------------------
__global__ void prep_kernel(const float* __restrict__ Mr,
                            const int* __restrict__ seg_ids,
                            float* __restrict__ rowsum,
                            int* __restrict__ seg_start) {
    int gtid = blockIdx.x * blockDim.x + threadIdx.x;
    if (gtid < RS_THREADS) {
        int row = gtid >> 4;
        int sub = gtid & 15;
        const float4* p = (const float4*)(Mr + (long)row * D_N);
        float4 v4 = p[sub];
        float v = v4.x + v4.y + v4.z + v4.w;
        v += __shfl_xor(v, 1);
        v += __shfl_xor(v, 2);
        v += __shfl_xor(v, 4);
        v += __shfl_xor(v, 8);
        if (sub == 0) rowsum[row] = v;
    } else {
        int t4 = gtid - RS_THREADS;
        if (t4 >= BD_THREADS) return;
        int base = t4 * 4;
        int4 s4 = ((const int4*)seg_ids)[t4];
        int sv0 = (base == 0) ? -1 : seg_ids[base - 1];
        int sv1 = s4.x, sv2 = s4.y, sv3 = s4.z, sv4 = s4.w;
        for (int s = sv0 + 1; s <= sv1; ++s) seg_start[s] = base + 0;
        for (int s = sv1 + 1; s <= sv2; ++s) seg_start[s] = base + 1;
        for (int s = sv2 + 1; s <= sv3; ++s) seg_start[s] = base + 2;
        for (int s = sv3 + 1; s <= sv4; ++s) seg_start[s] = base + 3;
        if (base + 4 == T_N) {
            for (int s = sv4 + 1; s <= NSEG; ++s) seg_start[s] = T_N;
        }
    }
}

// ---------------------------------------------------------------------------
// Kernel 2: one wave per sample. Emb dot computed inline (its HBM-miss
// latency overlaps the scan). Scan: one aligned int4 load per lane covers
// 256 elements (range avg = 100); ratings positional from the 6 boundaries;
// matches via cold ballot path; register accumulators; 18-shuffle epilogue.
// ---------------------------------------------------------------------------
__global__ void sample_kernel(const int* __restrict__ user_idx,
                              const int* __restrict__ item_idx,
                              const int* __restrict__ flat_items,
                              const float* __restrict__ user_emb,
                              const float* __restrict__ item_emb,
                              const float* __restrict__ user_bias,
                              const float* __restrict__ item_bias,
                              const float* __restrict__ global_avg,
                              const float* __restrict__ rowsum,
                              const int* __restrict__ seg_start,
                              float* __restrict__ out) {
    int lane = threadIdx.x & 63;
    int b    = (blockIdx.x * blockDim.x + threadIdx.x) >> 6;
    if (b >= B_N) return;

    int u      = user_idx[b];
    int target = item_idx[b];
    // issue the (likely HBM-miss) emb loads first so they overlap the scan
    float ue = user_emb[(long)u * D_N + lane];
    float ie = item_emb[(long)target * D_N + lane];

    int e0 = seg_start[b * R_N + 0];
    int e1 = seg_start[b * R_N + 1];
    int e2 = seg_start[b * R_N + 2];
    int e3 = seg_start[b * R_N + 3];
    int e4 = seg_start[b * R_N + 4];
    int e5 = seg_start[b * R_N + 5];
    int lo = e0, hi = e5;

    int base = lo & ~3;                  // 16B-aligned start
    int t0 = base + 4 * lane;

    int4 fi4 = make_int4(-1, -1, -1, -1);
    if (t0 < hi) fi4 = ((const int4*)(flat_items + base))[lane];
    int  fi[4] = {fi4.x, fi4.y, fi4.z, fi4.w};
    bool ok[4], mt[4];
    int  rj[4];
    float rv[4] = {0.f, 0.f, 0.f, 0.f};
    #pragma unroll
    for (int j = 0; j < 4; ++j) {
        int t = t0 + j;
        ok[j] = (t >= lo) & (t < hi);
        rj[j] = (t >= e1) + (t >= e2) + (t >= e3) + (t >= e4);
        mt[j] = ok[j] && (fi[j] == target);
    }
    #pragma unroll
    for (int j = 0; j < 4; ++j) {
        if (ok[j]) rv[j] = rowsum[fi[j]];
    }

    // ---- match counts (cold: matches ~0.001/sample) ----
    int mcnt[R_N] = {0, 0, 0, 0, 0};
    unsigned long long anym = __ballot(mt[0] | mt[1] | mt[2] | mt[3]);
    if (anym) {
        #pragma unroll
        for (int j = 0; j < 4; ++j) {
            #pragma unroll
            for (int r = 0; r < R_N; ++r) {
                mcnt[r] += __popcll(__ballot(mt[j] && rj[j] == r));
            }
        }
    }
    // rare tail: range longer than the 253+ covered by the int4 round
    for (int tb = base + 256; tb < hi; tb += 64) {
        int t = tb + lane;
        bool okt = t < hi;
        int f = okt ? flat_items[t] : -1;
        unsigned long long m = __ballot(okt && f == target);
        if (m) {
            int r = (t >= e1) + (t >= e2) + (t >= e3) + (t >= e4);
            #pragma unroll
            for (int rr = 0; rr < R_N; ++rr) {
                mcnt[rr] += __popcll(m & __ballot(r == rr));
            }
        }
    }

    // ---- per-rating weights (wave-uniform) ----
    int c0 = (e1 - e0) - mcnt[0];
    int c1 = (e2 - e1) - mcnt[1];
    int c2 = (e3 - e2) - mcnt[2];
    int c3 = (e4 - e3) - mcnt[3];
    int c4 = (e5 - e4) - mcnt[4];
    float w0 = c0 > 0 ? rsqrtf((float)c0) : 0.f;
    float w1 = c1 > 0 ? rsqrtf((float)c1) : 0.f;
    float w2 = c2 > 0 ? rsqrtf((float)c2) : 0.f;
    float w3 = c3 > 0 ? rsqrtf((float)c3) : 0.f;
    float w4 = c4 > 0 ? rsqrtf((float)c4) : 0.f;

    // ---- weighted accumulate (all in registers) ----
    float acc = 0.f;
    #pragma unroll
    for (int j = 0; j < 4; ++j) {
        if (ok[j] && !mt[j]) {
            int r = rj[j];
            float w = r == 0 ? w0 : (r == 1 ? w1 : (r == 2 ? w2 : (r == 3 ? w3 : w4)));
            acc += rv[j] * w;
        }
    }
    for (int tb = base + 256; tb < hi; tb += 64) {
        int t = tb + lane;
        if (t < hi) {
            int f = flat_items[t];
            if (f != target) {
                int r = (t >= e1) + (t >= e2) + (t >= e3) + (t >= e4);
                float w = r == 0 ? w0 : (r == 1 ? w1 : (r == 2 ? w2 : (r == 3 ? w3 : w4)));
                acc += rowsum[f] * w;
            }
        }
    }

    // ---- epilogue: reduce acc + dot + isum across the wave ----
    float dot = ue * ie;
    float isum = ie;
    #pragma unroll
    for (int off = 32; off >= 1; off >>= 1) {
        acc  += __shfl_xor(acc, off);
        dot  += __shfl_xor(dot, off);
        isum += __shfl_xor(isum, off);
    }
    if (lane == 0) {
        float rui = dot + acc * isum + user_bias[u] + item_bias[target] + global_avg[0];
        rui = fminf(fmaxf(rui, 1.0f), 5.0f);
        out[b] = rui;
    }
}

extern "C" void kernel_launch(void* const* d_in, const int* in_sizes, int n_in,
                              void* d_out, int out_size, void* d_ws, size_t ws_size,
                              hipStream_t stream) {
    const int*   user_idx   = (const int*)d_in[0];
    const int*   item_idx   = (const int*)d_in[1];
    const int*   flat_items = (const int*)d_in[2];
    const int*   seg_ids    = (const int*)d_in[3];
    const float* user_emb   = (const float*)d_in[4];
    const float* item_emb   = (const float*)d_in[5];
    const float* Mr         = (const float*)d_in[6];
    const float* user_bias  = (const float*)d_in[7];
    const float* item_bias  = (const float*)d_in[8];
    const float* global_avg = (const float*)d_in[9];
    float* out = (float*)d_out;

    // ws layout: [rowsum: I_N floats @0][seg_start: NSEG+1 ints @400000B]
    float* rowsum    = (float*)d_ws;
    int*   seg_start = (int*)((char*)d_ws + 400000);

    prep_kernel<<<(K1_THREADS + 255) / 256, 256, 0, stream>>>(
        Mr, seg_ids, rowsum, seg_start);
    sample_kernel<<<B_N / 4, 256, 0, stream>>>(
        user_idx, item_idx, flat_items, user_emb, item_emb,
        user_bias, item_bias, global_avg, rowsum, seg_start, out);
}

// Round 8
// 137.121 us; speedup vs baseline: 1.0274x; 1.0109x over previous
//
#include <hip/hip_runtime.h>

#define U_N 100000
#define I_N 100000
#define D_N 64
#define B_N 16384
#define T_N 1638400
#define R_N 5
#define NSEG (B_N * R_N)         // 81920 segments

#define RS_THREADS (I_N * 16)    // rowsum part: 16 threads/row
#define BD_THREADS (T_N / 4)     // boundary part: 4 elements/thread
#define K1_THREADS (RS_THREADS + BD_THREADS)

// ---------------------------------------------------------------------------
// Kernel 1 (fused): (a) rowsum[i] = sum_d Mr[i][d]; (b) scatter SEGMENT range
// starts: seg_start[s] = first t with seg_ids[t] >= s, for s in [0, NSEG],
// via linear transition scan of the sorted seg_ids. Every entry written.
// ---------------------------------------------------------------------------
__global__ void prep_kernel(const float* __restrict__ Mr,
                            const int* __restrict__ seg_ids,
                            float* __restrict__ rowsum,
                            int* __restrict__ seg_start) {
    int gtid = blockIdx.x * blockDim.x + threadIdx.x;
    if (gtid < RS_THREADS) {
        int row = gtid >> 4;
        int sub = gtid & 15;
        const float4* p = (const float4*)(Mr + (long)row * D_N);
        float4 v4 = p[sub];
        float v = v4.x + v4.y + v4.z + v4.w;
        v += __shfl_xor(v, 1);
        v += __shfl_xor(v, 2);
        v += __shfl_xor(v, 4);
        v += __shfl_xor(v, 8);
        if (sub == 0) rowsum[row] = v;
    } else {
        int t4 = gtid - RS_THREADS;
        if (t4 >= BD_THREADS) return;
        int base = t4 * 4;
        int4 s4 = ((const int4*)seg_ids)[t4];
        int sv0 = (base == 0) ? -1 : seg_ids[base - 1];
        int sv1 = s4.x, sv2 = s4.y, sv3 = s4.z, sv4 = s4.w;
        for (int s = sv0 + 1; s <= sv1; ++s) seg_start[s] = base + 0;
        for (int s = sv1 + 1; s <= sv2; ++s) seg_start[s] = base + 1;
        for (int s = sv2 + 1; s <= sv3; ++s) seg_start[s] = base + 2;
        for (int s = sv3 + 1; s <= sv4; ++s) seg_start[s] = base + 3;
        if (base + 4 == T_N) {
            for (int s = sv4 + 1; s <= NSEG; ++s) seg_start[s] = T_N;
        }
    }
}

// ---------------------------------------------------------------------------
// Kernel 2: one wave per sample. Rating of element t is positional (from the
// 6 segment boundaries), so seg_ids is never read. Matches are counted with
// wave-uniform ballot+popcount (cold path), giving exact per-rating counts
// BEFORE accumulation; each lane then folds rowsum*rsqrt(cnt_r) into a
// single accumulator. Predicated scalar loads (only in-range lanes issue
// requests — beats int4 here since data is L2-resident and the int4 variant
// quadruples request traffic). Epilogue reduces 3 values.
// ---------------------------------------------------------------------------
__device__ __forceinline__ void count_matches(unsigned long long m, int tb,
                                              int e0, int e1, int e2, int e3,
                                              int e4, int e5, int* mcnt) {
    if (m) {
        int ea[6] = {e0, e1, e2, e3, e4, e5};
        #pragma unroll
        for (int r = 0; r < 5; ++r) {
            int a = ea[r] - tb;     a = a < 0 ? 0 : (a > 64 ? 64 : a);
            int bb = ea[r + 1] - tb; bb = bb < 0 ? 0 : (bb > 64 ? 64 : bb);
            if (bb > a) {
                unsigned long long hiM = (bb == 64) ? ~0ULL : ((1ULL << bb) - 1ULL);
                unsigned long long loM = (1ULL << a) - 1ULL;
                mcnt[r] += __popcll(m & hiM & ~loM);
            }
        }
    }
}

__global__ void sample_kernel(const int* __restrict__ user_idx,
                              const int* __restrict__ item_idx,
                              const int* __restrict__ flat_items,
                              const float* __restrict__ user_emb,
                              const float* __restrict__ item_emb,
                              const float* __restrict__ user_bias,
                              const float* __restrict__ item_bias,
                              const float* __restrict__ global_avg,
                              const float* __restrict__ rowsum,
                              const int* __restrict__ seg_start,
                              float* __restrict__ out) {
    int lane = threadIdx.x & 63;
    int b    = (blockIdx.x * blockDim.x + threadIdx.x) >> 6;
    if (b >= B_N) return;

    int u      = user_idx[b];
    int target = item_idx[b];
    // issue the (likely HBM-miss) emb loads first so they overlap the scan
    float ue = user_emb[(long)u * D_N + lane];
    float ie = item_emb[(long)target * D_N + lane];

    int e0 = seg_start[b * R_N + 0];
    int e1 = seg_start[b * R_N + 1];
    int e2 = seg_start[b * R_N + 2];
    int e3 = seg_start[b * R_N + 3];
    int e4 = seg_start[b * R_N + 4];
    int e5 = seg_start[b * R_N + 5];
    int lo = e0, hi = e5;

    // ---- pass 1: register-cache first 128 elements, count matches ----
    int t0 = lo + lane, t1 = lo + 64 + lane;
    bool ok0 = t0 < hi, ok1 = t1 < hi;
    int fi0 = -1, fi1 = -1;
    float rv0 = 0.f, rv1 = 0.f;
    if (ok0) fi0 = flat_items[t0];
    if (ok1) fi1 = flat_items[t1];
    if (ok0) rv0 = rowsum[fi0];
    if (ok1) rv1 = rowsum[fi1];

    int mcnt[5] = {0, 0, 0, 0, 0};
    unsigned long long m0 = __ballot(ok0 && fi0 == target);
    unsigned long long m1 = __ballot(ok1 && fi1 == target);
    count_matches(m0, lo,      e0, e1, e2, e3, e4, e5, mcnt);
    count_matches(m1, lo + 64, e0, e1, e2, e3, e4, e5, mcnt);
    // rare tail (range > 128): count matches only
    for (int tb = lo + 128; tb < hi; tb += 64) {
        int t = tb + lane;
        bool ok = t < hi;
        int fi = ok ? flat_items[t] : -1;
        unsigned long long m = __ballot(ok && fi == target);
        count_matches(m, tb, e0, e1, e2, e3, e4, e5, mcnt);
    }

    // ---- per-rating weights (all lanes identical) ----
    int c0 = (e1 - e0) - mcnt[0];
    int c1 = (e2 - e1) - mcnt[1];
    int c2 = (e3 - e2) - mcnt[2];
    int c3 = (e4 - e3) - mcnt[3];
    int c4 = (e5 - e4) - mcnt[4];
    float w0 = c0 > 0 ? rsqrtf((float)c0) : 0.f;
    float w1 = c1 > 0 ? rsqrtf((float)c1) : 0.f;
    float w2 = c2 > 0 ? rsqrtf((float)c2) : 0.f;
    float w3 = c3 > 0 ? rsqrtf((float)c3) : 0.f;
    float w4 = c4 > 0 ? rsqrtf((float)c4) : 0.f;

    // ---- pass 2: weighted accumulate (registers for first 128, reload tail) ----
    float acc = 0.f;
    if (ok0 && fi0 != target) {
        float w = t0 >= e1 ? (t0 >= e2 ? (t0 >= e3 ? (t0 >= e4 ? w4 : w3) : w2) : w1) : w0;
        acc += rv0 * w;
    }
    if (ok1 && fi1 != target) {
        float w = t1 >= e1 ? (t1 >= e2 ? (t1 >= e3 ? (t1 >= e4 ? w4 : w3) : w2) : w1) : w0;
        acc += rv1 * w;
    }
    for (int tb = lo + 128; tb < hi; tb += 64) {
        int t = tb + lane;
        if (t < hi) {
            int fi = flat_items[t];
            if (fi != target) {
                float rv = rowsum[fi];
                float w = t >= e1 ? (t >= e2 ? (t >= e3 ? (t >= e4 ? w4 : w3) : w2) : w1) : w0;
                acc += rv * w;
            }
        }
    }

    // ---- epilogue: reduce 3 values across the wave ----
    float dot = ue * ie;
    float isum = ie;
    #pragma unroll
    for (int off = 32; off >= 1; off >>= 1) {
        acc  += __shfl_xor(acc, off);
        dot  += __shfl_xor(dot, off);
        isum += __shfl_xor(isum, off);
    }
    if (lane == 0) {
        float rui = dot + acc * isum + user_bias[u] + item_bias[target] + global_avg[0];
        rui = fminf(fmaxf(rui, 1.0f), 5.0f);
        out[b] = rui;
    }
}

extern "C" void kernel_launch(void* const* d_in, const int* in_sizes, int n_in,
                              void* d_out, int out_size, void* d_ws, size_t ws_size,
                              hipStream_t stream) {
    const int*   user_idx   = (const int*)d_in[0];
    const int*   item_idx   = (const int*)d_in[1];
    const int*   flat_items = (const int*)d_in[2];
    const int*   seg_ids    = (const int*)d_in[3];
    const float* user_emb   = (const float*)d_in[4];
    const float* item_emb   = (const float*)d_in[5];
    const float* Mr         = (const float*)d_in[6];
    const float* user_bias  = (const float*)d_in[7];
    const float* item_bias  = (const float*)d_in[8];
    const float* global_avg = (const float*)d_in[9];
    float* out = (float*)d_out;

    // ws layout: [rowsum: I_N floats][seg_start: NSEG+1 ints]
    float* rowsum    = (float*)d_ws;
    int*   seg_start = (int*)(rowsum + I_N);

    prep_kernel<<<(K1_THREADS + 255) / 256, 256, 0, stream>>>(
        Mr, seg_ids, rowsum, seg_start);
    sample_kernel<<<B_N / 4, 256, 0, stream>>>(
        user_idx, item_idx, flat_items, user_emb, item_emb,
        user_bias, item_bias, global_avg, rowsum, seg_start, out);
}